// Round 4
// baseline (240.671 us; speedup 1.0000x reference)
//
#include <hip/hip_runtime.h>

// EMA y_t = 0.1*x_t + 0.9*y_{t-1} along T of x[B=64][T=8192][F=64], fp32.
// R8: the store path is the serializer. Evidence: R4-R7 (4 structurally
// different kernels, all with scalar __builtin_nontemporal_store inside the
// chain) all land at 80-90us kernel, ~2.6 TB/s, VALUBusy 7%, per-iteration
// wait ~18k cycles >> 900cy HBM latency. Mechanism: vmcnt is ONE in-order
// counter for loads AND stores -> wait-for-loads transitively waits for
// prior nt-store retirement; nt stores drain at ~1.5 TB/s (vs 6.7 TB/s the
// harness fill kernel gets with plain stores). Fix:
//  - plain (not nt) stores;
//  - 4x wider stores: chain writes y rows to a wave-private LDS y-tile
//    (scalar ds_write, bank-free), then 4x global_store_dwordx4 per tile
//    (48 store instrs/wave instead of 192);
//  - issue order CHAIN -> LOADG(k+2) -> STOREY(k) -> WRITEX(k+1): the
//    load wait is vmcnt(8) (newest ops only); stores get a full iteration
//    of drain slack before anything can wait on them.
// Mapping unchanged (validated absmax 3.9e-3): 1 float/lane, wave = one
// (b,chunk) stream, L=128 stores, H=64 windup, chunk 0 exact.
// Grid 64b x 16 = 1024 blocks x 256 thr; LDS 32KB/block (x-tile + y-tile
// per wave, wave-private, zero __syncthreads).

typedef float fx4 __attribute__((ext_vector_type(4)));

constexpr int Tn = 8192;
constexpr int Fn = 64;    // features = lanes
constexpr int Ln = 128;   // stored rows per chunk
constexpr int Hn = 64;    // windup rows (0.9^64 ~ 1.2e-3 truncation)
constexpr int PF = 16;    // rows per staged tile (4KB)
constexpr float ALPHA = 0.1f;
constexpr float OMA   = 0.9f;

__global__ __launch_bounds__(256) void ema_kernel(const float* __restrict__ x,
                                                  float* __restrict__ y) {
    const int lane = threadIdx.x & 63;
    const int w    = threadIdx.x >> 6;             // wave in block 0..3
    const int b    = blockIdx.x >> 4;              // 0..63
    const int c    = ((blockIdx.x & 15) << 2) | w; // chunk 0..63

    const size_t bb = (size_t)b * (Tn * Fn);
    const float* __restrict__ xp = x + bb;
    float*       __restrict__ yp = y + bb;

    // wave-private tiles; every access below is byte-addr = lane*16 (wide)
    // or i*256 + lane*4 (scalar) -> conflict-free both directions.
    __shared__ float ldsx[4][PF * Fn];
    __shared__ float ldsy[4][PF * Fn];
    float* __restrict__ Lx = ldsx[w];
    float* __restrict__ Ly = ldsy[w];

    const int lr = lane >> 4;          // row-sub 0..3 within a 1KB access
    const int lf = (lane & 15) << 2;   // feature offset 0,4,..,60

    const int tstart = (c == 0) ? 0 : c * Ln - Hn;          // first staged row
    const int nb     = (c == 0) ? Ln / PF : (Ln + Hn) / PF; // 8 or 12
    const int sb     = (c == 0) ? 0 : Hn / PF;              // first stored batch

    // 4 independent coalesced 1KB loads: rows bt+4j+lr, feats lf..lf+3
    auto LOADG = [&](int bt, fx4& g0, fx4& g1, fx4& g2, fx4& g3) {
        const float* p = xp + (size_t)(bt + lr) * Fn + lf;
        g0 = *(const fx4*)(p);
        g1 = *(const fx4*)(p + 4 * Fn);
        g2 = *(const fx4*)(p + 8 * Fn);
        g3 = *(const fx4*)(p + 12 * Fn);
    };
    auto WRITEX = [&](fx4 g0, fx4 g1, fx4 g2, fx4 g3) {
        float* q = Lx + lr * Fn + lf;
        *(fx4*)(q)           = g0;
        *(fx4*)(q + 4 * Fn)  = g1;
        *(fx4*)(q + 8 * Fn)  = g2;
        *(fx4*)(q + 12 * Fn) = g3;
    };
    float s = 0.0f;
    // serial EMA chain over the staged tile; y rows -> LDS y-tile.
    auto CHAIN = [&](bool dostore, bool first) {
        #pragma unroll
        for (int i = 0; i < PF; ++i) {
            const float v = Lx[i * Fn + lane];
            if (first && i == 0) s = v;          // y_0 = x_0 exact
            else                 s = fmaf(OMA, s, ALPHA * v);
            if (dostore) Ly[i * Fn + lane] = s;
        }
    };
    // transpose y-tile back out with 4 plain 1KB stores
    auto STOREY = [&](int bt) {
        const float* q = Ly + lr * Fn + lf;
        const fx4 t0 = *(const fx4*)(q);
        const fx4 t1 = *(const fx4*)(q + 4 * Fn);
        const fx4 t2 = *(const fx4*)(q + 8 * Fn);
        const fx4 t3 = *(const fx4*)(q + 12 * Fn);
        float* o = yp + (size_t)(bt + lr) * Fn + lf;
        *(fx4*)(o)           = t0;
        *(fx4*)(o + 4 * Fn)  = t1;
        *(fx4*)(o + 8 * Fn)  = t2;
        *(fx4*)(o + 12 * Fn) = t3;
    };

    fx4 a0, a1, a2, a3, b0, b1, b2, b3;

    // prologue: batches 0 and 1 in flight; tile 0 staged.
    LOADG(tstart,      a0, a1, a2, a3);
    LOADG(tstart + PF, b0, b1, b2, b3);
    WRITEX(a0, a1, a2, a3);

    for (int k = 0; k < nb; ++k) {
        const bool st = (k >= sb);
        CHAIN(st, (c == 0) && (k == 0));
        if (k + 2 < nb) {                         // refill the freed regs
            if (k & 1) LOADG(tstart + (k + 2) * PF, b0, b1, b2, b3);
            else       LOADG(tstart + (k + 2) * PF, a0, a1, a2, a3);
        }
        if (st) STOREY(tstart + k * PF);
        if (k + 1 < nb) {                         // stage next tile
            if (k & 1) WRITEX(a0, a1, a2, a3);
            else       WRITEX(b0, b1, b2, b3);
        }
    }
}

extern "C" void kernel_launch(void* const* d_in, const int* in_sizes, int n_in,
                              void* d_out, int out_size, void* d_ws, size_t ws_size,
                              hipStream_t stream) {
    const float* x = (const float*)d_in[0];
    float*       y = (float*)d_out;
    // 64 b * 64 chunks = 4096 wave-streams; 4 waves (256 thr) per block;
    // all 4096 waves co-resident (16 waves/CU, 32KB LDS of 160KB).
    ema_kernel<<<dim3(1024), dim3(256), 0, stream>>>(x, y);
}

// Round 6
// 233.440 us; speedup vs baseline: 1.0310x; 1.0310x over previous
//
#include <hip/hip_runtime.h>

// EMA y_t = 0.1*x_t + 0.9*y_{t-1} along T of x[B=64][T=8192][F=64], fp32.
// R10 = R9 + the missing waitcnt. R9 read poison (absmax 1.2e37): the
// compiler does NOT insert a vmcnt wait between global_load_lds (retires on
// vmcnt) and ds_read (waits on lgkmcnt) -- in all guide examples that wait
// comes from __syncthreads()'s vmcnt(0) drain, and R9 is barrier-free.
// Fix: explicit inline-asm s_waitcnt vmcnt(N) + sched_barrier(0) (rule #18)
// between staging and the chain. Split wait for free overlap: issue all 32
// DMAs, vmcnt(16) -> windup half landed -> run 64 windup FMAs while live
// half streams in -> vmcnt(0) -> consume + store.
// Structure unchanged from R9: one wave = one chunk, straight-line, no
// barriers; 32x global_load_lds_dwordx4 (no dest regs -> compiler cannot
// collapse the batch; 32KB in flight per wave); [128][64] f32 linear tile
// (= gll's uniform-base + lane*16B layout); ds_read_b32 chain (bank =
// lane&31, 2-way free); scalar nt stores (256B coalesced).
// 8192 one-wave blocks, 32KB LDS -> 5 waves/CU -> 160KB DMA in flight/CU
// (~40MB chip) -> latency ceiling ~50 TB/s -> HBM-bound if theory holds.
// Numerics: H=64 windup (0.9^64 ~ 1.2e-3), chunk 0 exact (y_0 = x_0).

constexpr int Tn = 8192;
constexpr int Fn = 64;    // features = lanes
constexpr int Ln = 64;    // stored rows per wave
constexpr int Hn = 64;    // windup rows
constexpr int NC = Tn / Ln;  // 128 chunks per batch row
constexpr float ALPHA = 0.1f;
constexpr float OMA   = 0.9f;

#define AS_GLOBAL __attribute__((address_space(1)))
#define AS_LDS    __attribute__((address_space(3)))

__global__ __launch_bounds__(64) void ema_kernel(const float* __restrict__ x,
                                                 float* __restrict__ y) {
    // one wave per block; tile is wave-private -> zero __syncthreads
    __shared__ __align__(16) float tile[(Hn + Ln) * Fn];   // 32 KB

    const int lane = threadIdx.x;             // 0..63 = feature
    // XCD swizzle (bijective, 8192 = 8*1024): XCD k gets a contiguous
    // (b,c) range -> chunk-boundary windup re-reads are L2-local.
    const int wg = ((blockIdx.x & 7) << 10) | (blockIdx.x >> 3);
    const int b  = wg >> 7;                   // 0..63
    const int c  = wg & (NC - 1);             // 0..127

    const size_t bb = (size_t)b * (Tn * Fn);
    const float* __restrict__ xp = x + bb;
    float*       __restrict__ yp = y + bb;

    const int lr = lane >> 4;          // row-sub 0..3 within a 1KB DMA
    const int lf = (lane & 15) << 2;   // feature offset 0,4,..,60

    const int t0 = c * Ln;                          // first stored row
    const int tstart = (c == 0) ? 0 : t0 - Hn;      // first staged row

    float s;
    if (c != 0) {
        // ---- stage H+L rows: 32 DMAs, 32 KB, all in flight at once ----
        #pragma unroll
        for (int j = 0; j < (Hn + Ln) / 4; ++j) {
            const float* g = xp + (size_t)(tstart + 4 * j + lr) * Fn + lf;
            __builtin_amdgcn_global_load_lds(
                (const AS_GLOBAL float*)g,
                (AS_LDS float*)&tile[j * (4 * Fn)], 16, 0, 0);
        }
        // windup half (first 16 DMAs) landed:
        asm volatile("s_waitcnt vmcnt(16)" ::: "memory");
        __builtin_amdgcn_sched_barrier(0);
        // windup rows 0..Hn-1 (no stores) while live half streams in;
        // truncation error <= 0.9^64 ~ 1.2e-3
        s = 0.0f;
        #pragma unroll
        for (int i = 0; i < Hn; ++i)
            s = fmaf(OMA, s, ALPHA * tile[i * Fn + lane]);
        // live half landed:
        asm volatile("s_waitcnt vmcnt(0)" ::: "memory");
        __builtin_amdgcn_sched_barrier(0);
        #pragma unroll
        for (int i = 0; i < Ln; ++i) {
            s = fmaf(OMA, s, ALPHA * tile[(Hn + i) * Fn + lane]);
            __builtin_nontemporal_store(s, &yp[(size_t)(t0 + i) * Fn + lane]);
        }
    } else {
        // ---- chunk 0 exact: 16 DMAs, then y_0 = x_0 ----
        #pragma unroll
        for (int j = 0; j < Ln / 4; ++j) {
            const float* g = xp + (size_t)(4 * j + lr) * Fn + lf;
            __builtin_amdgcn_global_load_lds(
                (const AS_GLOBAL float*)g,
                (AS_LDS float*)&tile[j * (4 * Fn)], 16, 0, 0);
        }
        asm volatile("s_waitcnt vmcnt(0)" ::: "memory");
        __builtin_amdgcn_sched_barrier(0);
        s = tile[lane];
        __builtin_nontemporal_store(s, &yp[lane]);
        #pragma unroll
        for (int i = 1; i < Ln; ++i) {
            s = fmaf(OMA, s, ALPHA * tile[i * Fn + lane]);
            __builtin_nontemporal_store(s, &yp[(size_t)i * Fn + lane]);
        }
    }
}

extern "C" void kernel_launch(void* const* d_in, const int* in_sizes, int n_in,
                              void* d_out, int out_size, void* d_ws, size_t ws_size,
                              hipStream_t stream) {
    const float* x = (const float*)d_in[0];
    float*       y = (float*)d_out;
    // 64 b * 128 chunks = 8192 one-wave blocks (64 thr each).
    ema_kernel<<<dim3(8192), dim3(64), 0, stream>>>(x, y);
}